// Round 6
// baseline (7998.306 us; speedup 1.0000x reference)
//
#include <hip/hip_runtime.h>
#include <math.h>

typedef _Float16 half_t;
typedef _Float16 half8 __attribute__((ext_vector_type(8)));
typedef float f32x4 __attribute__((ext_vector_type(4)));

#define B_ 128
#define T_ 256
#define I_ 512
#define H_ 1024

// ---------------------------------------------------------------------------
// sync: 8 sub-counters per (layer,step), each on its own 64B line.
// Spin RELAXED (no per-iteration L2 invalidate!), then ONE acquire load.
__device__ __forceinline__ void wait_all8(int* base) {
#pragma unroll 1
    for (int g = 0; g < 8; ++g) {
        int* p = base + g * 16;
        while (__hip_atomic_load(p, __ATOMIC_RELAXED, __HIP_MEMORY_SCOPE_AGENT) < 16)
            __builtin_amdgcn_s_sleep(1);
    }
    (void)__hip_atomic_load(base, __ATOMIC_ACQUIRE, __HIP_MEMORY_SCOPE_AGENT);
}
__device__ __forceinline__ void publish8(int* base, int g) {
    __hip_atomic_fetch_add(base + g * 16, 1, __ATOMIC_RELEASE, __HIP_MEMORY_SCOPE_AGENT);
}

// ---------------------------------------------------------------------------
// prep: x fp32 [b][t][i] -> fp16 transposed [t][b][i]
__global__ void k_convert_x(const float* __restrict__ x, half_t* __restrict__ x16t, int n8) {
    int i = blockIdx.x * blockDim.x + threadIdx.x;
    if (i >= n8) return;
    int col8 = i & 63;   // I/8 = 64
    int bt = i >> 6;     // b*T + t
    int b = bt >> 8;     // T = 256
    int t = bt & 255;
    const float4* xv = (const float4*)(x + (size_t)bt * I_);
    float4 a = xv[col8 * 2], c = xv[col8 * 2 + 1];
    half8 o;
    o[0] = (half_t)a.x; o[1] = (half_t)a.y; o[2] = (half_t)a.z; o[3] = (half_t)a.w;
    o[4] = (half_t)c.x; o[5] = (half_t)c.y; o[6] = (half_t)c.z; o[7] = (half_t)c.w;
    ((half8*)(x16t + ((size_t)t * B_ + b) * I_))[col8] = o;
}

// Pack W_ih|W_hh into per-(slice s, K-quarter kh, gate-pair gp) B-frag slabs:
// [s(64)][kh(4)][gp(2)][kb(NKBW)][nt(2)][lane(64)][j(8)], NKBW = Ktot/128.
// (layout validated round 5)
__global__ void k_pack_w4(const float* __restrict__ Wih, const float* __restrict__ Whh,
                          half_t* __restrict__ out, int Kx, int Ktot) {
    long long idx = blockIdx.x * (long long)blockDim.x + threadIdx.x;
    long long total = 4096LL * Ktot;
    if (idx >= total) return;
    int NKBW = Ktot >> 7;
    int j = idx & 7;
    int lane = (idx >> 3) & 63;
    int nt = (idx >> 9) & 1;
    int kb = (int)((idx >> 10) % NKBW);
    int rest = (int)((idx >> 10) / NKBW);
    int gp = rest & 1, kh = (rest >> 1) & 3, s = rest >> 3;
    int gate = gp * 2 + nt;
    int row = gate * 1024 + s * 16 + (lane & 15);
    int k = kh * (Ktot >> 2) + kb * 32 + ((lane >> 4) << 3) + j;
    float v = (k < Kx) ? Wih[(size_t)row * Kx + k] : Whh[(size_t)row * 1024 + (k - Kx)];
    out[idx] = (half_t)v;
}

// bias packed bp[s*64 + gate*16 + hoff] (validated round 5)
__global__ void k_pack_bias3(const float* __restrict__ bih, const float* __restrict__ bhh,
                             float* __restrict__ out) {
    int idx = blockIdx.x * blockDim.x + threadIdx.x;
    if (idx >= 4096) return;
    int s = idx >> 6, c = idx & 63;
    int nt = c >> 4, hoff = c & 15;
    int row = nt * 1024 + s * 16 + hoff;
    out[idx] = bih[row] + bhh[row];
}

__global__ void k_zero(unsigned int* __restrict__ p, int n) {
    int i = blockIdx.x * blockDim.x + threadIdx.x;
    if (i < n) p[i] = 0u;
}

__global__ void k_seed8(int* c0, int* c1) {
    int g = threadIdx.x;
    if (g < 8) { c0[g * 16] = 16; c1[g * 16] = 16; }
}

// ---------------------------------------------------------------------------
// WG = (layer, slice s in [0,64), row-half rh). 512 threads = 8 waves:
// wave = kh*2 + gp; wave holds a DISTINCT B chunk (32 cols x K/4) in regs.
// Per step: phase A = non-recurrent K-part (L0: x; L1: own h1 recurrence,
// gated by cnt1[t] which is a step old) -> ONE wait -> phase B = recurrent
// K-part. K-merge via LDS (validated round 5), register epilogue, nt stores.
template <int LAYER, int NKBW, bool PERSIST>
__device__ __forceinline__ void layer_run(
    int s, int rh, int g, const half_t* __restrict__ x16t,
    half_t* __restrict__ h0seq, half_t* __restrict__ h1seq,
    const half_t* __restrict__ wp, const float* __restrict__ bp,
    float* __restrict__ cbuf, int* cnt0, int* cnt1, int t0, int t1,
    float (*pbufR)[64][68], float (*pf)[68]) {
    constexpr int KTOT = NKBW * 128;
    constexpr int K4 = KTOT / 4;
    constexpr int KX = LAYER ? 1024 : 512;

    int tid = threadIdx.x;
    int wave = tid >> 6, lane = tid & 63;
    int gp = wave & 1, kh = wave >> 1;
    int q = lane >> 4, ml = lane & 15;

    // distinct B chunk -> VGPRs (once)
    half8 Breg[NKBW][2];
    {
        const half8* w8 = (const half8*)wp;
        size_t base = (size_t)((s * 8 + kh * 2 + gp) * NKBW) * 128;
#pragma unroll
        for (int kb = 0; kb < NKBW; ++kb) {
            Breg[kb][0] = w8[base + kb * 128 + lane];
            Breg[kb][1] = w8[base + kb * 128 + 64 + lane];
        }
    }

    float c_r[2] = {0.f, 0.f};
    float bias_r[2][4];
#pragma unroll
    for (int e = 0; e < 2; ++e) {
        int h = (tid + 512 * e) & 15;
#pragma unroll
        for (int gg = 0; gg < 4; ++gg) bias_r[e][gg] = bp[s * 64 + gg * 16 + h];
        if (!PERSIST) {
            int r = (tid + 512 * e) >> 4;
            c_r[e] = cbuf[LAYER * (B_ * H_) + (rh * 64 + r) * H_ + s * 16 + h];
        }
    }

    for (int t = t0; t < t1; ++t) {
        const half_t* ax[4];  // L0: x16t[t] ; L1: h0seq[t+1]
        const half_t* ah[4];  // L0: h0seq[t]; L1: h1seq[t]
#pragma unroll
        for (int mt = 0; mt < 4; ++mt) {
            int row = rh * 64 + mt * 16 + ml;
            if (LAYER == 0) {
                ax[mt] = x16t + ((size_t)t * B_ + row) * I_;
                ah[mt] = h0seq + ((size_t)t * B_ + row) * H_;
            } else {
                ax[mt] = h0seq + ((size_t)(t + 1) * B_ + row) * H_;
                ah[mt] = h1seq + ((size_t)t * B_ + row) * H_;
            }
        }

        f32x4 acc[4][2];
#pragma unroll
        for (int mt = 0; mt < 4; ++mt) { acc[mt][0] = (f32x4)0.f; acc[mt][1] = (f32x4)0.f; }

        // L1 phase-A input (own recurrence) gate: cnt1[t], a step old ~free
        if (LAYER == 1 && PERSIST) {
            if (tid == 0) wait_all8(cnt1 + t * 128);
            __syncthreads();
        }

        // ---- phase A: non-recurrent K-part ----
#pragma unroll
        for (int kb = 0; kb < NKBW; ++kb) {
            int kgu = kh * K4 + kb * 32;  // wave-uniform
            bool inA = (LAYER == 0) ? (kgu < KX) : (kgu >= KX);
            if (!inA) continue;
            int k = kgu + q * 8;
#pragma unroll
            for (int mt = 0; mt < 4; ++mt) {
                const half_t* ap = (LAYER == 0) ? ax[mt] + k : ah[mt] + (k - KX);
                half8 a = *(const half8*)ap;
                acc[mt][0] = __builtin_amdgcn_mfma_f32_16x16x32_f16(a, Breg[kb][0], acc[mt][0], 0, 0, 0);
                acc[mt][1] = __builtin_amdgcn_mfma_f32_16x16x32_f16(a, Breg[kb][1], acc[mt][1], 0, 0, 0);
            }
        }

        // ---- the wait: recurrent input ready? ----
        if (PERSIST) {
            if (tid == 0) wait_all8(LAYER == 0 ? cnt0 + t * 128 : cnt0 + (t + 1) * 128);
            __syncthreads();
        }

        // ---- phase B: recurrent K-part ----
#pragma unroll
        for (int kb = 0; kb < NKBW; ++kb) {
            int kgu = kh * K4 + kb * 32;
            bool inB = (LAYER == 0) ? (kgu >= KX) : (kgu < KX);
            if (!inB) continue;
            int k = kgu + q * 8;
#pragma unroll
            for (int mt = 0; mt < 4; ++mt) {
                const half_t* ap = (LAYER == 0) ? ah[mt] + (k - KX) : ax[mt] + k;
                half8 a = *(const half8*)ap;
                acc[mt][0] = __builtin_amdgcn_mfma_f32_16x16x32_f16(a, Breg[kb][0], acc[mt][0], 0, 0, 0);
                acc[mt][1] = __builtin_amdgcn_mfma_f32_16x16x32_f16(a, Breg[kb][1], acc[mt][1], 0, 0, 0);
            }
        }

        // ---- K-merge (C/D: col=lane&15, row=q*4+r; validated r5) ----
        if (kh >= 2) {
#pragma unroll
            for (int mt = 0; mt < 4; ++mt)
#pragma unroll
                for (int nt = 0; nt < 2; ++nt)
#pragma unroll
                    for (int r = 0; r < 4; ++r)
                        pbufR[kh - 2][mt * 16 + q * 4 + r][gp * 32 + nt * 16 + ml] = acc[mt][nt][r];
        }
        __syncthreads();
        if (kh == 0) {
#pragma unroll
            for (int mt = 0; mt < 4; ++mt)
#pragma unroll
                for (int nt = 0; nt < 2; ++nt)
#pragma unroll
                    for (int r = 0; r < 4; ++r)
                        acc[mt][nt][r] += pbufR[0][mt * 16 + q * 4 + r][gp * 32 + nt * 16 + ml];
        } else if (kh == 1) {
#pragma unroll
            for (int mt = 0; mt < 4; ++mt)
#pragma unroll
                for (int nt = 0; nt < 2; ++nt)
#pragma unroll
                    for (int r = 0; r < 4; ++r) {
                        int rr = mt * 16 + q * 4 + r, cc = gp * 32 + nt * 16 + ml;
                        pbufR[1][rr][cc] += acc[mt][nt][r];
                    }
        }
        __syncthreads();
        if (kh == 0) {
#pragma unroll
            for (int mt = 0; mt < 4; ++mt)
#pragma unroll
                for (int nt = 0; nt < 2; ++nt)
#pragma unroll
                    for (int r = 0; r < 4; ++r) {
                        int rr = mt * 16 + q * 4 + r, cc = gp * 32 + nt * 16 + ml;
                        pf[rr][cc] = acc[mt][nt][r] + pbufR[1][rr][cc];
                    }
        }
        __syncthreads();

        // ---- epilogue: 2 cells/thread, state in regs, nontemporal h store ----
        half_t* hout = LAYER ? h1seq : h0seq;
#pragma unroll
        for (int e = 0; e < 2; ++e) {
            int idx = tid + 512 * e;
            int r = idx >> 4, h = idx & 15;
            float gi = pf[r][h] + bias_r[e][0];
            float gf = pf[r][16 + h] + bias_r[e][1];
            float gg = pf[r][32 + h] + bias_r[e][2];
            float go = pf[r][48 + h] + bias_r[e][3];
            float si = 1.f / (1.f + __expf(-gi));
            float sf = 1.f / (1.f + __expf(-gf));
            float so = 1.f / (1.f + __expf(-go));
            float tg = 1.f - 2.f / (__expf(2.f * gg) + 1.f);
            float cn = sf * c_r[e] + si * tg;
            float th = 1.f - 2.f / (__expf(2.f * cn) + 1.f);
            c_r[e] = cn;
            __builtin_nontemporal_store(
                (half_t)(so * th),
                &hout[((size_t)(t + 1) * B_ + rh * 64 + r) * H_ + s * 16 + h]);
        }

        if (PERSIST) {
            __syncthreads();  // all waves' stores drained (vmcnt0 before barrier)
            if (tid == 0) publish8((LAYER ? cnt1 : cnt0) + (t + 1) * 128, g);
        }
    }

    if (!PERSIST) {
#pragma unroll
        for (int e = 0; e < 2; ++e) {
            int idx = tid + 512 * e;
            int r = idx >> 4, h = idx & 15;
            cbuf[LAYER * (B_ * H_) + (rh * 64 + r) * H_ + s * 16 + h] = c_r[e];
        }
    }
}

__global__ __launch_bounds__(512, 2) void lstm_persist(
    const half_t* __restrict__ x16t, half_t* __restrict__ h0seq, half_t* __restrict__ h1seq,
    const half_t* __restrict__ wp0, const half_t* __restrict__ wp1,
    const float* __restrict__ b0p, const float* __restrict__ b1p,
    float* __restrict__ cbuf, int* cnt0, int* cnt1) {
    __shared__ float pbufR[2][64][68];
    __shared__ float pf[64][68];
    int bid = blockIdx.x;
    int wid = bid & 127;
    int s = wid >> 1, rh = bid & 1, g = wid & 7;
    if (bid < 128)
        layer_run<0, 12, true>(s, rh, g, x16t, h0seq, h1seq, wp0, b0p, cbuf, cnt0, cnt1, 0, T_, pbufR, pf);
    else
        layer_run<1, 16, true>(s, rh, g, x16t, h0seq, h1seq, wp1, b1p, cbuf, cnt0, cnt1, 0, T_, pbufR, pf);
}

// fallback: launch k does L0 step k and L1 step k-1 (stream-ordered pipeline)
__global__ __launch_bounds__(512, 2) void lstm_step_fb(
    int k, const half_t* __restrict__ x16t, half_t* __restrict__ h0seq,
    half_t* __restrict__ h1seq, const half_t* __restrict__ wp0,
    const half_t* __restrict__ wp1, const float* __restrict__ b0p,
    const float* __restrict__ b1p, float* __restrict__ cbuf) {
    __shared__ float pbufR[2][64][68];
    __shared__ float pf[64][68];
    int bid = blockIdx.x;
    int s = (bid & 127) >> 1, rh = bid & 1;
    if (bid < 128) {
        if (k >= T_) return;
        layer_run<0, 12, false>(s, rh, 0, x16t, h0seq, h1seq, wp0, b0p, cbuf, 0, 0, k, k + 1, pbufR, pf);
    } else {
        if (k < 1) return;
        layer_run<1, 16, false>(s, rh, 0, x16t, h0seq, h1seq, wp1, b1p, cbuf, 0, 0, k - 1, k, pbufR, pf);
    }
}

// final FC
__global__ void k_fc(const half_t* __restrict__ h, const float* __restrict__ Wfc,
                     const float* __restrict__ bfc, float* __restrict__ out) {
    int m = blockIdx.x, lane = threadIdx.x;
    float s = 0.f;
    for (int k = lane; k < H_; k += 64) s += (float)h[m * H_ + k] * Wfc[k];
#pragma unroll
    for (int o = 32; o; o >>= 1) s += __shfl_down(s, o, 64);
    if (lane == 0) out[m] = s + bfc[0];
}

// ---------------------------------------------------------------------------
extern "C" void kernel_launch(void* const* d_in, const int* in_sizes, int n_in,
                              void* d_out, int out_size, void* d_ws, size_t ws_size,
                              hipStream_t stream) {
    const float* x    = (const float*)d_in[0];
    const float* Wih0 = (const float*)d_in[1];
    const float* Whh0 = (const float*)d_in[2];
    const float* bih0 = (const float*)d_in[3];
    const float* bhh0 = (const float*)d_in[4];
    const float* Wih1 = (const float*)d_in[5];
    const float* Whh1 = (const float*)d_in[6];
    const float* bih1 = (const float*)d_in[7];
    const float* bhh1 = (const float*)d_in[8];
    const float* Wfc  = (const float*)d_in[9];
    const float* bfc  = (const float*)d_in[10];
    float* out = (float*)d_out;

    char* ws = (char*)d_ws;
    size_t off = 0;
    auto carve = [&](size_t bytes) { void* p = ws + off; off += (bytes + 255) & ~(size_t)255; return p; };
    half_t* x16t  = (half_t*)carve((size_t)B_ * T_ * I_ * 2);        // 33.6 MB
    half_t* h0seq = (half_t*)carve((size_t)(T_ + 1) * B_ * H_ * 2);  // 67.4 MB
    half_t* h1seq = (half_t*)carve((size_t)(T_ + 1) * B_ * H_ * 2);  // 67.4 MB
    half_t* wp0   = (half_t*)carve((size_t)4096 * 1536 * 2);         // 12.6 MB
    half_t* wp1   = (half_t*)carve((size_t)4096 * 2048 * 2);         // 16.8 MB
    float*  b0p   = (float*)carve(4096 * 4);
    float*  b1p   = (float*)carve(4096 * 4);
    float*  cbuf  = (float*)carve((size_t)2 * B_ * H_ * 4);          // 1 MB
    int*    flags = (int*)carve((size_t)2 * 257 * 128 * 4);          // 263 KB
    if (off > ws_size) return;  // ~199 MB; round-2 proved ws >= 215 MB

    int* cnt0 = flags;                 // [257][8 x 16-int-padded]
    int* cnt1 = flags + 257 * 128;

    k_convert_x<<<(B_ * T_ * I_ / 8 + 255) / 256, 256, 0, stream>>>(x, x16t, B_ * T_ * I_ / 8);
    k_pack_w4<<<(4096 * 1536 + 255) / 256, 256, 0, stream>>>(Wih0, Whh0, wp0, 512, 1536);
    k_pack_w4<<<(4096 * 2048 + 255) / 256, 256, 0, stream>>>(Wih1, Whh1, wp1, 1024, 2048);
    k_pack_bias3<<<16, 256, 0, stream>>>(bih0, bhh0, b0p);
    k_pack_bias3<<<16, 256, 0, stream>>>(bih1, bhh1, b1p);
    k_zero<<<256, 256, 0, stream>>>((unsigned int*)h0seq, 65536);   // t=0 slot
    k_zero<<<256, 256, 0, stream>>>((unsigned int*)h1seq, 65536);   // t=0 slot
    k_zero<<<1024, 256, 0, stream>>>((unsigned int*)cbuf, 262144);
    k_zero<<<(2 * 257 * 128 + 255) / 256, 256, 0, stream>>>((unsigned int*)flags, 2 * 257 * 128);
    k_seed8<<<1, 8, 0, stream>>>(cnt0, cnt1);

    void* args[] = {(void*)&x16t, (void*)&h0seq, (void*)&h1seq, (void*)&wp0, (void*)&wp1,
                    (void*)&b0p, (void*)&b1p, (void*)&cbuf, (void*)&cnt0, (void*)&cnt1};
    hipError_t err = hipLaunchCooperativeKernel((void*)lstm_persist, dim3(256), dim3(512),
                                                args, 0, stream);
    if (err != hipSuccess) {
        (void)hipGetLastError();  // clear sticky error; pipelined fallback
        for (int k = 0; k < T_ + 1; ++k)
            lstm_step_fb<<<256, 512, 0, stream>>>(k, x16t, h0seq, h1seq, wp0, wp1,
                                                  b0p, b1p, cbuf);
    }

    k_fc<<<128, 64, 0, stream>>>(h1seq + (size_t)T_ * B_ * H_, Wfc, bfc, out);
}